// Round 2
// 7481.734 us; speedup vs baseline: 1.4979x; 1.4979x over previous
//
#include <hip/hip_runtime.h>
#include <stdint.h>

// Problem constants
#define BB 128
#define TT 1024
#define II 256
#define HH 256
#define G4 1024   // 4*H

#define Y1_DEPTH 16  // y1 inter-layer ring depth (power of 2)

typedef __attribute__((ext_vector_type(8))) short short8;
typedef __attribute__((ext_vector_type(4))) float float4v;

__device__ __forceinline__ unsigned short f2bf(float f) {
  union { float f; unsigned u; } v; v.f = f;
  unsigned u = v.u + 0x7FFFu + ((v.u >> 16) & 1u);  // RNE; inputs finite
  return (unsigned short)(u >> 16);
}

__device__ __forceinline__ float sigm(float x) { return 1.f / (1.f + __expf(-x)); }
__device__ __forceinline__ float tanhfast(float x) { return 2.f / (1.f + __expf(-2.f * x)) - 1.f; }

// ---------------------------------------------------------------------------
// MALL-coherent exchange primitives. sc0 sc1 = bypass L1 AND the per-XCD L2;
// the op executes at the memory-side Infinity Cache, which is physically
// shared by all XCDs -> coherent across blocks with NO fences. This replaces
// the baseline's agent-scope acquire/release fences, whose L1+L2 invalidation
// forced ~1.3 MB/step of HBM re-fetch (FETCH_SIZE evidence) and serialized
// every step on HBM latency.
// ---------------------------------------------------------------------------
__device__ __forceinline__ int poll_mall(const int* p) {
  int v;
  asm volatile("global_load_dword %0, %1, off sc0 sc1\n\ts_waitcnt vmcnt(0)"
               : "=v"(v) : "v"(p) : "memory");
  return v;
}
__device__ __forceinline__ short8 ld_mall_b128(const unsigned short* p) {
  short8 v;
  asm volatile("global_load_dwordx4 %0, %1, off sc0 sc1" : "=v"(v) : "v"(p));
  return v;
}
__device__ __forceinline__ void st_mall_u16(unsigned short* p, unsigned int v) {
  asm volatile("global_store_short %0, %1, off sc0 sc1" :: "v"(p), "v"(v) : "memory");
}
__device__ __forceinline__ void post_mall(int* p) {
  asm volatile("global_atomic_add %0, %1, off sc1" :: "v"(p), "v"(1) : "memory");
}

// Pre-pass: x [B,T,I] fp32 -> xbf [T,B,I] bf16 (time-major, MFMA-ready).
// Removes ~128 f2bf conversions per thread per step from the serial
// recurrence and makes each step's x slice contiguous.
__global__ __launch_bounds__(256) void xprep(const float* __restrict__ x,
                                             unsigned short* __restrict__ xbf) {
  size_t i = ((size_t)blockIdx.x * 256 + threadIdx.x) * 8;  // exact cover
  int k = (int)(i & (size_t)(II - 1));
  size_t bt = i >> 8;                 // II = 256
  int t = (int)(bt & (size_t)(TT - 1));
  int b = (int)(bt >> 10);            // TT = 1024
  float4v v0 = *(const float4v*)(x + i);
  float4v v1 = *(const float4v*)(x + i + 4);
  short8 s;
  s[0] = (short)f2bf(v0[0]); s[1] = (short)f2bf(v0[1]);
  s[2] = (short)f2bf(v0[2]); s[3] = (short)f2bf(v0[3]);
  s[4] = (short)f2bf(v1[0]); s[5] = (short)f2bf(v1[1]);
  s[6] = (short)f2bf(v1[2]); s[7] = (short)f2bf(v1[3]);
  *(short8*)(xbf + ((size_t)t * BB + b) * II + k) = s;
}

// 64 persistent blocks (proven round-0 structure):
// [layer(2)] x [batch-group(4), 32 rows] x [gate-slice(8), 32 j].
// Per step: GEMM M=32,N=128,K=512 via mfma_f32_16x16x32_bf16, weights
// LDS-resident, c-state in registers, h/y1/flags exchanged via MALL (sc1).
__global__ __launch_bounds__(256, 1) void vlstm(
    const float* __restrict__ x, const float* __restrict__ W_ih,
    const float* __restrict__ W_hh, const float* __restrict__ b_ih,
    const float* __restrict__ b_hh, const float* __restrict__ masks,
    float* __restrict__ out, int* __restrict__ flags,
    unsigned short* __restrict__ hstate, unsigned short* __restrict__ y1ring,
    const unsigned short* __restrict__ xbf, int use_xbf)
{
  const int tid = threadIdx.x;
  const int bid = blockIdx.x;
  const int layer = bid >> 5;          // 0..1
  const int bg = (bid >> 3) & 3;       // batch group 0..3 (32 rows)
  const int gs = bid & 7;              // gate j-slice 0..7 (32 j)
  const int bbase = bg * 32, jbase = gs * 32;

  __shared__ unsigned short Wlds[128][520];   // 133,120 B (pad kills conflicts)
  __shared__ float gsh[32][136];              //  17,408 B
  __shared__ float bias_sh[128];              //     512 B  -> 151,040 <= 160K

  // ---- one-time: stage weight slice (rows n = jl*4+q -> global q*H+jbase+jl)
  const float* Wih_l = W_ih + (size_t)layer * G4 * II;
  const float* Whh_l = W_hh + (size_t)layer * G4 * HH;
  for (int e = tid; e < 128 * 512; e += 256) {
    int n = e >> 9, c = e & 511;
    int r = (n & 3) * HH + jbase + (n >> 2);
    float w = (c < 256) ? Wih_l[(size_t)r * II + c] : Whh_l[(size_t)r * HH + (c - 256)];
    Wlds[n][c] = f2bf(w);
  }
  if (tid < 128) {
    int r = (tid & 3) * HH + jbase + (tid >> 2);
    bias_sh[tid] = b_ih[layer * G4 + r] + b_hh[layer * G4 + r];
  }

  // ---- per-thread elementwise state ----
  float cst[4], m_out[4], m_h[4], m_c[4];
  const float* mk = masks + (size_t)layer * 3 * BB * HH;
  #pragma unroll
  for (int r = 0; r < 4; ++r) {
    int idx = r * 256 + tid;
    int m = idx >> 5, jl = idx & 31;
    int b = bbase + m, j = jbase + jl;
    m_out[r] = mk[(size_t)b * HH + j];
    m_h[r]   = mk[(size_t)BB * HH + (size_t)b * HH + j];
    m_c[r]   = mk[(size_t)2 * BB * HH + (size_t)b * HH + j];
    cst[r] = 0.f;
  }
  __syncthreads();

  const int wv = tid >> 6;       // wave 0..3 -> owns 32 gate-cols
  const int lane = tid & 63;
  const int lr = lane & 15;      // A-row / B-col within 16x16 tile
  const int lg = lane >> 4;      // k-group (8 consecutive k)

  int* fown = flags + (layer * 4 + bg) * TT;  // this octet's per-step flags
  int* fin  = flags + bg * TT;                // layer-0 octet (y1_t ready)
  int* fl2  = flags + (4 + bg) * TT;          // layer-1 octet (ring slot free)
  unsigned short* hs_l = hstate + (size_t)layer * 2 * BB * HH;

  // Global spin budget: any sync failure terminates in ~2 s with wrong
  // results (bench reports mismatch) instead of a livelock/abort.
  int budget = 1 << 23;

  #pragma unroll 1
  for (int t = 0; t < TT; ++t) {
    // ---- pre-issue x loads (flag-independent; latency hides under spin) --
    short8 afrag[2][16];   // K-concat: kt 0..7 = x|y1 part, 8..15 = h part
    if (layer == 0) {
      #pragma unroll
      for (int mt = 0; mt < 2; ++mt) {
        const int b = bbase + mt * 16 + lr;
        if (use_xbf) {
          const unsigned short* xp = xbf + ((size_t)t * BB + b) * II + lg * 8;
          #pragma unroll
          for (int kt = 0; kt < 8; ++kt)
            afrag[mt][kt] = *(const short8*)(xp + kt * 32);
        } else {
          const float* xp = x + ((size_t)b * TT + t) * II + lg * 8;
          #pragma unroll
          for (int kt = 0; kt < 8; ++kt) {
            float4v v0 = *(const float4v*)(xp + kt * 32);
            float4v v1 = *(const float4v*)(xp + kt * 32 + 4);
            short8 s;
            s[0] = (short)f2bf(v0[0]); s[1] = (short)f2bf(v0[1]);
            s[2] = (short)f2bf(v0[2]); s[3] = (short)f2bf(v0[3]);
            s[4] = (short)f2bf(v1[0]); s[5] = (short)f2bf(v1[1]);
            s[6] = (short)f2bf(v1[2]); s[7] = (short)f2bf(v1[3]);
            afrag[mt][kt] = s;
          }
        }
      }
    }

    // ---- waits: octet done t-1; layer1: y1_t ready; layer0: slot free ----
    if (tid == 0) {
      if (t > 0)           while (budget > 0) { --budget; if (poll_mall(fown + t - 1) >= 8) break; }
      if (layer == 1)      { while (budget > 0) { --budget; if (poll_mall(fin + t) >= 8) break; } }
      else if (t >= Y1_DEPTH) { while (budget > 0) { --budget; if (poll_mall(fl2 + t - Y1_DEPTH) >= 8) break; } }
    }
    __syncthreads();

    const unsigned short* hread = hs_l + (size_t)((t + 1) & 1) * BB * HH;

    // ---- h (and y1 for layer1) fragments straight from MALL ----
    #pragma unroll
    for (int mt = 0; mt < 2; ++mt) {
      const int b = bbase + mt * 16 + lr;
      if (layer == 1) {
        const unsigned short* yp =
            y1ring + ((size_t)(t & (Y1_DEPTH - 1)) * BB + b) * HH + lg * 8;
        #pragma unroll
        for (int kt = 0; kt < 8; ++kt) afrag[mt][kt] = ld_mall_b128(yp + kt * 32);
      }
      const unsigned short* hp = hread + (size_t)b * HH + lg * 8;
      #pragma unroll
      for (int kt = 0; kt < 8; ++kt) afrag[mt][8 + kt] = ld_mall_b128(hp + kt * 32);
    }
    asm volatile("s_waitcnt vmcnt(0)" ::: "memory");  // asm loads are untracked
    __builtin_amdgcn_sched_barrier(0);                // keep MFMAs below (rule #18)

    // ---- MFMA: gates[m][n] = sum_k A[m][k] * W[n][k], per wave N=32 ----
    float4v acc[2][2] = {};
    #pragma unroll
    for (int kt = 0; kt < 16; ++kt) {
      #pragma unroll
      for (int nt = 0; nt < 2; ++nt) {
        short8 bfrag = *(const short8*)&Wlds[wv * 32 + nt * 16 + lr][kt * 32 + lg * 8];
        #pragma unroll
        for (int mt = 0; mt < 2; ++mt)
          acc[mt][nt] = __builtin_amdgcn_mfma_f32_16x16x32_bf16(
              afrag[mt][kt], bfrag, acc[mt][nt], 0, 0, 0);
      }
    }

    // ---- gates -> LDS (C/D layout: col=lane&15, row=(lane>>4)*4+reg) ----
    #pragma unroll
    for (int mt = 0; mt < 2; ++mt)
      #pragma unroll
      for (int nt = 0; nt < 2; ++nt)
        #pragma unroll
        for (int rg = 0; rg < 4; ++rg)
          gsh[mt * 16 + lg * 4 + rg][wv * 32 + nt * 16 + lr] = acc[mt][nt][rg];
    __syncthreads();   // no vm ops outstanding here: costs nothing extra

    // ---- elementwise LSTM cell; h/y1 go out via sc1 write-through ----
    unsigned short* hwrite = hs_l + (size_t)(t & 1) * BB * HH;
    #pragma unroll
    for (int r = 0; r < 4; ++r) {
      int idx = r * 256 + tid;
      int m = idx >> 5, jl = idx & 31;
      float4v g4 = *(const float4v*)&gsh[m][jl * 4];
      float gi = sigm(g4[0] + bias_sh[jl * 4 + 0]);
      float gf = sigm(g4[1] + bias_sh[jl * 4 + 1]);
      float gg = tanhfast(g4[2] + bias_sh[jl * 4 + 2]);
      float go = sigm(g4[3] + bias_sh[jl * 4 + 3]);
      float c2 = gf * cst[r] + gi * gg;
      float h2 = go * tanhfast(c2);
      cst[r] = c2 * m_c[r];                              // carried c (fp32)
      int b = bbase + m, j = jbase + jl;
      st_mall_u16(&hwrite[(size_t)b * HH + j], f2bf(h2 * m_h[r]));
      if (layer == 0)
        st_mall_u16(&y1ring[((size_t)(t & (Y1_DEPTH - 1)) * BB + b) * HH + j],
                    f2bf(h2 * m_out[r]));
      else
        out[((size_t)b * TT + t) * HH + j] = h2 * m_out[r];  // plain: kernel-end flush
    }
    // Drain sc1 stores (compiler can't see asm vm ops) before the barrier,
    // then post the flag: MALL order guarantees data-before-flag.
    asm volatile("s_waitcnt vmcnt(0)" ::: "memory");
    __syncthreads();
    if (tid == 0) post_mall(fown + t);
  }
}

extern "C" void kernel_launch(void* const* d_in, const int* in_sizes, int n_in,
                              void* d_out, int out_size, void* d_ws, size_t ws_size,
                              hipStream_t stream) {
  const float* x     = (const float*)d_in[0];
  const float* W_ih  = (const float*)d_in[1];
  const float* W_hh  = (const float*)d_in[2];
  const float* b_ih  = (const float*)d_in[3];
  const float* b_hh  = (const float*)d_in[4];
  const float* masks = (const float*)d_in[5];
  float* out = (float*)d_out;

  const size_t FLAG_BYTES = (size_t)2 * 4 * TT * sizeof(int);                  //  32 KB
  const size_t HS_BYTES   = (size_t)2 * 2 * BB * HH * sizeof(unsigned short);  // 256 KB
  const size_t Y1_BYTES   = (size_t)Y1_DEPTH * BB * HH * sizeof(unsigned short); // 1 MB
  const size_t BASE       = FLAG_BYTES + HS_BYTES + Y1_BYTES;
  const size_t XBF_BYTES  = (size_t)TT * BB * II * sizeof(unsigned short);     // 64 MB
  const int use_xbf = (ws_size >= BASE + XBF_BYTES) ? 1 : 0;

  int* flags = (int*)d_ws;
  unsigned short* hstate = (unsigned short*)((char*)d_ws + FLAG_BYTES);
  unsigned short* y1ring = (unsigned short*)((char*)d_ws + FLAG_BYTES + HS_BYTES);
  unsigned short* xbf    = (unsigned short*)((char*)d_ws + BASE);

  // zero flags + h + y1 (ws is poisoned 0xAA before every launch)
  hipMemsetAsync(d_ws, 0, BASE, stream);
  if (use_xbf)
    xprep<<<dim3((BB * TT * II / 8) / 256), dim3(256), 0, stream>>>(x, xbf);
  vlstm<<<dim3(64), dim3(256), 0, stream>>>(x, W_ih, W_hh, b_ih, b_hh, masks,
                                            out, flags, hstate, y1ring,
                                            xbf, use_xbf);
}

// Round 4
// 6874.768 us; speedup vs baseline: 1.6301x; 1.0883x over previous
//
#include <hip/hip_runtime.h>
#include <stdint.h>

// Problem constants
#define BB 128
#define TT 1024
#define II 256
#define HH 256
#define G4 1024   // 4*H

#define Y1_DEPTH 16  // y1 inter-layer ring depth (power of 2)

typedef __attribute__((ext_vector_type(8))) short short8;
typedef __attribute__((ext_vector_type(4))) float float4v;

__device__ __forceinline__ unsigned short f2bf(float f) {
  union { float f; unsigned u; } v; v.f = f;
  unsigned u = v.u + 0x7FFFu + ((v.u >> 16) & 1u);  // RNE; inputs finite
  return (unsigned short)(u >> 16);
}
__device__ __forceinline__ float sigm(float x) { return 1.f / (1.f + __expf(-x)); }
__device__ __forceinline__ float tanhfast(float x) { return 2.f / (1.f + __expf(-2.f * x)) - 1.f; }

__device__ __forceinline__ unsigned long long pack4bf(float a, float b, float c, float d) {
  return (unsigned long long)f2bf(a) | ((unsigned long long)f2bf(b) << 16) |
         ((unsigned long long)f2bf(c) << 32) | ((unsigned long long)f2bf(d) << 48);
}

// ---------------------------------------------------------------------------
// MALL-coherent exchange (round-2 proven): sc0 sc1 ops bypass L1 and the
// per-XCD L2 and execute at the shared Infinity Cache -> cross-XCD coherent
// with NO fences, NO cache invalidation (weights/x stay cached).
// ---------------------------------------------------------------------------
__device__ __forceinline__ short8 ld128_mall(const unsigned short* p) {
  short8 v;
  asm volatile("global_load_dwordx4 %0, %1, off sc0 sc1" : "=v"(v) : "v"(p));
  return v;
}
__device__ __forceinline__ void st64_mall(unsigned short* p, unsigned long long v) {
  asm volatile("global_store_dwordx2 %0, %1, off sc0 sc1" :: "v"(p), "v"(v) : "memory");
}
__device__ __forceinline__ void post_mall(int* p) {
  asm volatile("global_atomic_add %0, %1, off sc1" :: "v"(p), "v"(1) : "memory");
}

// Pre-pass: x [B,T,I] fp32 -> xbf [T,B,I] bf16 (time-major, MFMA-ready).
__global__ __launch_bounds__(256) void xprep(const float* __restrict__ x,
                                             unsigned short* __restrict__ xbf) {
  size_t i = ((size_t)blockIdx.x * 256 + threadIdx.x) * 8;  // exact cover
  int k = (int)(i & (size_t)(II - 1));
  size_t bt = i >> 8;                 // II = 256
  int t = (int)(bt & (size_t)(TT - 1));
  int b = (int)(bt >> 10);            // TT = 1024
  float4v v0 = *(const float4v*)(x + i);
  float4v v1 = *(const float4v*)(x + i + 4);
  short8 s;
  s[0] = (short)f2bf(v0[0]); s[1] = (short)f2bf(v0[1]);
  s[2] = (short)f2bf(v0[2]); s[3] = (short)f2bf(v0[3]);
  s[4] = (short)f2bf(v1[0]); s[5] = (short)f2bf(v1[1]);
  s[6] = (short)f2bf(v1[2]); s[7] = (short)f2bf(v1[3]);
  *(short8*)(xbf + ((size_t)t * BB + b) * II + k) = s;
}

// 64 persistent blocks (round-2 proven structure):
// [layer(2)] x [batch-group(4), 32 rows] x [gate-slice(8), 32 j].
// Per step: GEMM M=32,N=128,K=512 via mfma_f32_16x16x32_bf16, weights
// LDS-resident, c-state in registers, h/y1/flags exchanged via MALL (sc1).
// New this round (latency-safe only): packed 8B state stores, combined
// 2-deep rolling flag poll, y1 pre-issue, x prefetch, counted-waitcnt
// raw barriers. No new coherence mechanisms.
__global__ __launch_bounds__(256, 1) void vlstm(
    const float* __restrict__ x, const float* __restrict__ W_ih,
    const float* __restrict__ W_hh, const float* __restrict__ b_ih,
    const float* __restrict__ b_hh, const float* __restrict__ masks,
    float* __restrict__ out, int* __restrict__ flags,
    unsigned short* __restrict__ hstate, unsigned short* __restrict__ y1ring,
    const unsigned short* __restrict__ xbf, int use_xbf)
{
  const int tid = threadIdx.x;
  const int bid = blockIdx.x;
  const int layer = bid >> 5;          // 0..1
  const int bg = (bid >> 3) & 3;       // batch group 0..3 (32 rows)
  const int gs = bid & 7;              // gate j-slice 0..7 (32 j)
  const int bbase = bg * 32, jbase = gs * 32;

  __shared__ unsigned short Wlds[128][520];   // 133,120 B (pad kills conflicts)
  __shared__ float gsh[32][132];              //  16,896 B
  __shared__ float bias_sh[128];              //     512 B
  __shared__ int s_y1n[2];

  if (tid == 0) { s_y1n[0] = 0; s_y1n[1] = 0; }

  // ---- one-time: stage weight slice (rows n = jl*4+q -> global q*H+jbase+jl)
  const float* Wih_l = W_ih + (size_t)layer * G4 * II;
  const float* Whh_l = W_hh + (size_t)layer * G4 * HH;
  for (int e = tid; e < 128 * 512; e += 256) {
    int n = e >> 9, c = e & 511;
    int r = (n & 3) * HH + jbase + (n >> 2);
    float w = (c < 256) ? Wih_l[(size_t)r * II + c] : Whh_l[(size_t)r * HH + (c - 256)];
    Wlds[n][c] = f2bf(w);
  }
  if (tid < 128) {
    int r = (tid & 3) * HH + jbase + (tid >> 2);
    bias_sh[tid] = b_ih[layer * G4 + r] + b_hh[layer * G4 + r];
  }

  const int wv = tid >> 6;       // wave 0..3 -> owns 32 gate-cols
  const int lane = tid & 63;
  const int lr = lane & 15;      // A-row / B-col within 16x16 tile
  const int lg = lane >> 4;      // k-group (8 consecutive k)
  const int em = tid >> 3;       // elementwise row 0..31
  const int eq = tid & 7;        // elementwise j-quad 0..7

  // ---- per-thread elementwise state (j = jbase + eq*4 + r) ----
  float cst[4], m_out[4], m_h[4], m_c[4];
  {
    const float* mk = masks + (size_t)layer * 3 * BB * HH;
    #pragma unroll
    for (int r = 0; r < 4; ++r) {
      int b = bbase + em, j = jbase + eq * 4 + r;
      m_out[r] = mk[(size_t)b * HH + j];
      m_h[r]   = mk[(size_t)BB * HH + (size_t)b * HH + j];
      m_c[r]   = mk[(size_t)2 * BB * HH + (size_t)b * HH + j];
      cst[r] = 0.f;
    }
  }
  __syncthreads();

  int* fown = flags + (layer * 4 + bg) * TT;  // this octet's per-step flags
  int* fcA  = flags + (8 + bg) * TT;          // layer0->layer1: y1[t] drained
  int* fcB  = flags + (12 + bg) * TT;         // layer1->layer0: slot consumed
  unsigned short* hs_l = hstate + (size_t)layer * 2 * BB * HH;

  short8 afrag[2][16];   // kt 0..7 = x|y1 part, 8..15 = h part
  auto load_afx = [&](int t) {
    #pragma unroll
    for (int mt = 0; mt < 2; ++mt) {
      const int b = bbase + mt * 16 + lr;
      if (use_xbf) {
        const unsigned short* xp = xbf + ((size_t)t * BB + b) * II + lg * 8;
        #pragma unroll
        for (int kt = 0; kt < 8; ++kt)
          afrag[mt][kt] = *(const short8*)(xp + kt * 32);
      } else {
        const float* xp = x + ((size_t)b * TT + t) * II + lg * 8;
        #pragma unroll
        for (int kt = 0; kt < 8; ++kt) {
          float4v v0 = *(const float4v*)(xp + kt * 32);
          float4v v1 = *(const float4v*)(xp + kt * 32 + 4);
          short8 s;
          s[0] = (short)f2bf(v0[0]); s[1] = (short)f2bf(v0[1]);
          s[2] = (short)f2bf(v0[2]); s[3] = (short)f2bf(v0[3]);
          s[4] = (short)f2bf(v1[0]); s[5] = (short)f2bf(v1[1]);
          s[6] = (short)f2bf(v1[2]); s[7] = (short)f2bf(v1[3]);
          afrag[mt][kt] = s;
        }
      }
    }
  };
  if (layer == 0) load_afx(0);

  int budget = 1 << 24;   // global spin budget: fail finite, never hang

  #pragma unroll 1
  for (int t = 0; t < TT; ++t) {
    // ---- layer1: pre-issue y1[t] loads if readiness was observed at t-1 --
    int y1pre = 0;
    if (layer == 1) {
      y1pre = s_y1n[t & 1];
      if (y1pre) {
        #pragma unroll
        for (int mt = 0; mt < 2; ++mt) {
          const unsigned short* yp =
              y1ring + ((size_t)(t & (Y1_DEPTH - 1)) * BB + bbase + mt * 16 + lr) * HH + lg * 8;
          #pragma unroll
          for (int kt = 0; kt < 8; ++kt)
            afrag[mt][kt] = ld128_mall(yp + kt * 32);
        }
      }
    }

    // ---- combined 2-deep rolling poll (detection granularity ~RT/2) ----
    if (tid == 0) {
      int need_own = (t > 0) ? 1 : 0;
      int need_in  = (layer == 1) ? 1 : 0;
      int need_sl  = (layer == 0 && t >= Y1_DEPTH) ? 1 : 0;
      const int probe = (layer == 1 && t + 1 < TT) ? 1 : 0;
      int y1n = 0;
      if (need_own | need_in | need_sl) {
        const int* w0 = need_own ? fown + (t - 1)      : fown + t;
        const int* w1 = need_in  ? fcA + t             : fown + t;
        const int* w2 = need_sl  ? fcB + (t - Y1_DEPTH): fown + t;
        const int* w3 = probe    ? fcA + (t + 1)       : fown + t;
        int a0, a1, a2, a3, b0, b1, b2, b3;
#define ISSUE4(r0, r1, r2, r3)                                   \
        asm volatile("global_load_dword %0, %4, off sc0 sc1\n\t" \
                     "global_load_dword %1, %5, off sc0 sc1\n\t" \
                     "global_load_dword %2, %6, off sc0 sc1\n\t" \
                     "global_load_dword %3, %7, off sc0 sc1"     \
                     : "=&v"(r0), "=&v"(r1), "=&v"(r2), "=&v"(r3)\
                     : "v"(w0), "v"(w1), "v"(w2), "v"(w3) : "memory")
        ISSUE4(a0, a1, a2, a3);
        ISSUE4(b0, b1, b2, b3);
        while (true) {
          // outstanding <=4 -> batch A (older) fully retired (in-order vmcnt)
          asm volatile("s_waitcnt vmcnt(4)" ::: "memory");
          __builtin_amdgcn_sched_barrier(0);
          if (a0 >= 8) need_own = 0;
          if (a1 >= 8) need_in  = 0;
          if (a2 >= 8) need_sl  = 0;
          if (a3 >= 8) y1n = 1;
          if (!(need_own | need_in | need_sl)) break;
          if (--budget < 0) break;
          ISSUE4(a0, a1, a2, a3);
          asm volatile("s_waitcnt vmcnt(4)" ::: "memory");
          __builtin_amdgcn_sched_barrier(0);
          if (b0 >= 8) need_own = 0;
          if (b1 >= 8) need_in  = 0;
          if (b2 >= 8) need_sl  = 0;
          if (b3 >= 8) y1n = 1;
          if (!(need_own | need_in | need_sl)) break;
          if (--budget < 0) break;
          ISSUE4(b0, b1, b2, b3);
        }
#undef ISSUE4
      }
      s_y1n[(t + 1) & 1] = y1n;   // consumed by all threads at step t+1
    }
    __syncthreads();

    const unsigned short* hread = hs_l + (size_t)((t + 1) & 1) * BB * HH;

    // ---- h (and late y1 for layer1) fragments straight from MALL ----
    #pragma unroll
    for (int mt = 0; mt < 2; ++mt) {
      const int b = bbase + mt * 16 + lr;
      if (layer == 1 && !y1pre) {
        const unsigned short* yp =
            y1ring + ((size_t)(t & (Y1_DEPTH - 1)) * BB + b) * HH + lg * 8;
        #pragma unroll
        for (int kt = 0; kt < 8; ++kt) afrag[mt][kt] = ld128_mall(yp + kt * 32);
      }
      const unsigned short* hp = hread + (size_t)b * HH + lg * 8;
      #pragma unroll
      for (int kt = 0; kt < 8; ++kt)
        afrag[mt][8 + kt] = ld128_mall(hp + kt * 32);
    }
    asm volatile("s_waitcnt vmcnt(0)" ::: "memory");  // asm loads untracked
    __builtin_amdgcn_sched_barrier(0);                // pin MFMAs below

    // ---- MFMA: gates[m][n] = sum_k A[m][k] * W[n][k], per wave N=32 ----
    float4v acc[2][2] = {};
    #pragma unroll
    for (int kt = 0; kt < 16; ++kt) {
      #pragma unroll
      for (int nt = 0; nt < 2; ++nt) {
        short8 bfrag = *(const short8*)&Wlds[wv * 32 + nt * 16 + lr][kt * 32 + lg * 8];
        #pragma unroll
        for (int mt = 0; mt < 2; ++mt)
          acc[mt][nt] = __builtin_amdgcn_mfma_f32_16x16x32_bf16(
              afrag[mt][kt], bfrag, acc[mt][nt], 0, 0, 0);
      }
    }

    // ---- gates -> LDS (C/D layout: col=lane&15, row=(lane>>4)*4+reg) ----
    #pragma unroll
    for (int mt = 0; mt < 2; ++mt)
      #pragma unroll
      for (int nt = 0; nt < 2; ++nt)
        #pragma unroll
        for (int rg = 0; rg < 4; ++rg)
          gsh[mt * 16 + lg * 4 + rg][wv * 32 + nt * 16 + lr] = acc[mt][nt][rg];
    // raw barrier with LDS-only drain (no vmcnt(0): keeps pipeline intact)
    asm volatile("s_waitcnt lgkmcnt(0)" ::: "memory");
    __builtin_amdgcn_s_barrier();
    __builtin_amdgcn_sched_barrier(0);

    // ---- elementwise LSTM cell on a j-quad; packed 8B state stores ----
    unsigned short* hwrite = hs_l + (size_t)(t & 1) * BB * HH;
    float hh2[4];
    #pragma unroll
    for (int r = 0; r < 4; ++r) {
      float4v g4 = *(const float4v*)&gsh[em][eq * 16 + r * 4];
      float gi = sigm(g4[0] + bias_sh[eq * 16 + r * 4 + 0]);
      float gf = sigm(g4[1] + bias_sh[eq * 16 + r * 4 + 1]);
      float gg = tanhfast(g4[2] + bias_sh[eq * 16 + r * 4 + 2]);
      float go = sigm(g4[3] + bias_sh[eq * 16 + r * 4 + 3]);
      float c2 = gf * cst[r] + gi * gg;
      hh2[r] = go * tanhfast(c2);
      cst[r] = c2 * m_c[r];
    }
    {
      // h store FIRST (oldest) so vmcnt(1) below guarantees its retirement
      // at the MALL before the flag post (in-order vmcnt, m135).
      unsigned long long hp4 = pack4bf(hh2[0] * m_h[0], hh2[1] * m_h[1],
                                       hh2[2] * m_h[2], hh2[3] * m_h[3]);
      st64_mall(hwrite + (size_t)(bbase + em) * HH + jbase + eq * 4, hp4);
      if (layer == 0) {
        unsigned long long yp4 = pack4bf(hh2[0] * m_out[0], hh2[1] * m_out[1],
                                         hh2[2] * m_out[2], hh2[3] * m_out[3]);
        st64_mall(y1ring + ((size_t)(t & (Y1_DEPTH - 1)) * BB + bbase + em) * HH
                      + jbase + eq * 4, yp4);
      } else {
        float4v ov;
        ov[0] = hh2[0] * m_out[0]; ov[1] = hh2[1] * m_out[1];
        ov[2] = hh2[2] * m_out[2]; ov[3] = hh2[3] * m_out[3];
        *(float4v*)(out + ((size_t)(bbase + em) * TT + t) * HH + jbase + eq * 4) = ov;
      }
    }
    // vmcnt(1): h (older) retired at the MALL; the newest store (y1/out) may
    // stay in flight — it is NOT gated by fown. Raw barrier: no full drain.
    asm volatile("s_waitcnt vmcnt(1) lgkmcnt(0)" ::: "memory");
    __builtin_amdgcn_s_barrier();
    __builtin_amdgcn_sched_barrier(0);
    if (tid == 0) {
      post_mall(fown + t);
      // layer0: y1[t-1] retired (older than this step's h, in-order vmcnt).
      if (layer == 0) { if (t > 0) post_mall(fcA + (t - 1)); }
      // layer1: y1[t] reads completed at this step's pre-MFMA vmcnt(0).
      else post_mall(fcB + t);
    }
    // prefetch next x under the next wait (plain tracked loads)
    if (layer == 0 && t + 1 < TT) load_afx(t + 1);
  }

  // tail: final cross-layer post (after full drain)
  asm volatile("s_waitcnt vmcnt(0)" ::: "memory");
  __syncthreads();
  if (tid == 0 && layer == 0) post_mall(fcA + (TT - 1));
}

extern "C" void kernel_launch(void* const* d_in, const int* in_sizes, int n_in,
                              void* d_out, int out_size, void* d_ws, size_t ws_size,
                              hipStream_t stream) {
  const float* x     = (const float*)d_in[0];
  const float* W_ih  = (const float*)d_in[1];
  const float* W_hh  = (const float*)d_in[2];
  const float* b_ih  = (const float*)d_in[3];
  const float* b_hh  = (const float*)d_in[4];
  const float* masks = (const float*)d_in[5];
  float* out = (float*)d_out;

  const size_t FLAG_BYTES = (size_t)16 * TT * sizeof(int);                     //  64 KB
  const size_t HS_BYTES   = (size_t)2 * 2 * BB * HH * sizeof(unsigned short);  // 256 KB
  const size_t Y1_BYTES   = (size_t)Y1_DEPTH * BB * HH * sizeof(unsigned short); // 1 MB
  const size_t BASE       = FLAG_BYTES + HS_BYTES + Y1_BYTES;
  const size_t XBF_BYTES  = (size_t)TT * BB * II * sizeof(unsigned short);     // 64 MB
  const int use_xbf = (ws_size >= BASE + XBF_BYTES) ? 1 : 0;

  int* flags = (int*)d_ws;
  unsigned short* hstate = (unsigned short*)((char*)d_ws + FLAG_BYTES);
  unsigned short* y1ring = (unsigned short*)((char*)d_ws + FLAG_BYTES + HS_BYTES);
  unsigned short* xbf    = (unsigned short*)((char*)d_ws + BASE);

  // zero flags + h + y1 (ws is poisoned 0xAA before every launch)
  hipMemsetAsync(d_ws, 0, BASE, stream);
  if (use_xbf)
    xprep<<<dim3((BB * TT * II / 8) / 256), dim3(256), 0, stream>>>(x, xbf);
  vlstm<<<dim3(64), dim3(256), 0, stream>>>(x, W_ih, W_hh, b_ih, b_hh, masks,
                                            out, flags, hstate, y1ring,
                                            xbf, use_xbf);
}